// Round 3
// baseline (133.483 us; speedup 1.0000x reference)
//
#include <hip/hip_runtime.h>

// LatencyEncoder R2: two-kernel split.
//  K1 zero_fill: clone of __amd_rocclr_fillBufferAligned's shape (grid-stride
//     float4 stores, no reads/LDS/selects, minimal VGPRs) -- that kernel
//     measures 6.8-7.0 TB/s on this very buffer; 419.4 MB => ~61 us.
//  K2 spike_scatter: recompute latency per pair (f64 chain, matches np ref,
//     absmax 0.0 in R0/R1) and store one 1.0f dword for spiking pairs only
//     (~0.5M scattered dwords). Stream order puts these after the zeroes.

#define T 100

__global__ __launch_bounds__(256) void zero_fill_kernel(float4* __restrict__ o4, int n4) {
  const int stride = gridDim.x * 256;
  const float4 z = make_float4(0.f, 0.f, 0.f, 0.f);
  for (int i = blockIdx.x * 256 + threadIdx.x; i < n4; i += stride) o4[i] = z;
}

__global__ __launch_bounds__(256) void spike_scatter_kernel(
    const float* __restrict__ x, const float* __restrict__ noise,
    float* __restrict__ out, int npairs) {
  const int stride = gridDim.x * 256;
  for (int p = blockIdx.x * 256 + threadIdx.x; p < npairs; p += stride) {
    // decision chain in f64 to match the numpy reference exactly
    double xn = (double)x[p] + (double)noise[p] * 0.01;
    double s  = 1.0 / (1.0 + exp(-xn));
    if (s > 0.5) {
      int li = (int)rint((1.0 - s) * 99.0);
      li = li < 0 ? 0 : (li > 99 ? 99 : li);
      out[(long long)p * T + li] = 1.0f;
    }
  }
}

extern "C" void kernel_launch(void* const* d_in, const int* in_sizes, int n_in,
                              void* d_out, int out_size, void* d_ws, size_t ws_size,
                              hipStream_t stream) {
  const float* x = (const float*)d_in[0];
  const float* noise = (const float*)d_in[1];
  float* out = (float*)d_out;
  const int npairs = in_sizes[0];        // 1,048,576
  const int n4 = out_size / 4;           // 26,214,400 float4s (out_size % 4 == 0)

  // K1: 2048 blocks * 4 waves = 8192 waves = 32/CU; ~50 float4 stores/thread.
  zero_fill_kernel<<<2048, 256, 0, stream>>>((float4*)out, n4);
  // K2: grid-stride over pairs, 4 pairs/thread.
  spike_scatter_kernel<<<1024, 256, 0, stream>>>(x, noise, out, npairs);
}

// Round 5
// 85.424 us; speedup vs baseline: 1.5626x; 1.5626x over previous
//
#include <hip/hip_runtime.h>

// LatencyEncoder R4 = R3 with the nontemporal store compile fix:
// __builtin_nontemporal_store requires a NATIVE vector type, not
// HIP_vector_type<float,4>. Use ext_vector_type(4) float.
//
// Rationale (unchanged): output stream is 419.4 MB write-once/no-reuse; plain
// stores write-allocate every line in L2 (13x the 32 MB L2). rocclr fill hits
// 6.85 TB/s on this buffer (floor ~66us); R0 at 5.0 TB/s. nt stores mark lines
// no-allocate/evict-first. Spike is embedded in the stream via selects.
//
// Structure (unchanged from R0, best passing: 85us, absmax 0.0):
//  - 256-thread block owns 256 consecutive pairs.
//  - Phase 1: per-pair latency in f64 (matches numpy ref bit-exactly) -> LDS.
//  - Phase 2: block writes its contiguous 25,600-float region as 6400 float4s,
//    thread t writes float4 t + k*256 (coalesced 1 KB/wave/instr).

#define TIME_STEPS 100
#define PAIRS_PER_BLOCK 256
#define F4_PER_PAIR (TIME_STEPS / 4)                 // 25
#define F4_PER_THREAD (PAIRS_PER_BLOCK * F4_PER_PAIR / 256)  // 25

typedef float vf4 __attribute__((ext_vector_type(4)));

__global__ __launch_bounds__(256) void latency_encode_kernel(
    const float* __restrict__ x, const float* __restrict__ noise,
    float* __restrict__ out, int npairs) {
  __shared__ int lat_s[PAIRS_PER_BLOCK];

  const int tid = threadIdx.x;
  const int pairBase = blockIdx.x * PAIRS_PER_BLOCK;
  const int p = pairBase + tid;

  // ---- Phase 1: per-pair latency in f64 (match numpy f64 reference) ----
  int lat = -1;
  if (p < npairs) {
    double xn = (double)x[p] + (double)noise[p] * 0.01;
    double s = 1.0 / (1.0 + exp(-xn));
    int li = (int)rint((1.0 - s) * 99.0);
    li = li < 0 ? 0 : (li > 99 ? 99 : li);
    lat = (s > 0.5) ? li : -1;  // -1: no spike, row stays all-zero
  }
  lat_s[tid] = lat;
  __syncthreads();

  // ---- Phase 2: coalesced nontemporal float4 writes ----
  vf4* o4 = (vf4*)(out + (size_t)pairBase * TIME_STEPS);
#pragma unroll
  for (int k = 0; k < F4_PER_THREAD; ++k) {
    const int fi4 = tid + k * 256;            // consecutive across lanes
    const int pl = fi4 / F4_PER_PAIR;         // pair-local index 0..255
    const int pos = (fi4 % F4_PER_PAIR) * 4;  // element offset within pair
    const int L = lat_s[pl];
    vf4 v;
    v.x = (L == pos + 0) ? 1.0f : 0.0f;
    v.y = (L == pos + 1) ? 1.0f : 0.0f;
    v.z = (L == pos + 2) ? 1.0f : 0.0f;
    v.w = (L == pos + 3) ? 1.0f : 0.0f;
    if (pairBase + pl < npairs) __builtin_nontemporal_store(v, &o4[fi4]);
  }
}

extern "C" void kernel_launch(void* const* d_in, const int* in_sizes, int n_in,
                              void* d_out, int out_size, void* d_ws, size_t ws_size,
                              hipStream_t stream) {
  const float* x = (const float*)d_in[0];
  const float* noise = (const float*)d_in[1];
  float* out = (float*)d_out;
  const int npairs = in_sizes[0];  // 256*4096
  const int grid = (npairs + PAIRS_PER_BLOCK - 1) / PAIRS_PER_BLOCK;
  latency_encode_kernel<<<grid, 256, 0, stream>>>(x, noise, out, npairs);
}